// Round 5
// baseline (543.280 us; speedup 1.0000x reference)
//
#include <hip/hip_runtime.h>

#define KSTATE 64
#define NSAMP  1024

__device__ __forceinline__ float bcast0(float x) {
  return __int_as_float(__builtin_amdgcn_readfirstlane(__float_as_int(x)));
}

// One wave (64 threads): row-softmax of T -> expT, log_softmax(pi) -> log_pi, zero out.
__global__ __launch_bounds__(64) void hmm_preproc(
    const float* __restrict__ pi, const float* __restrict__ T,
    float* __restrict__ expT, float* __restrict__ log_pi,
    float* __restrict__ out) {
  const int lane = threadIdx.x;
  float m = -3.4e38f;
  for (int k = 0; k < KSTATE; ++k) m = fmaxf(m, T[lane * KSTATE + k]);
  float s = 0.f;
  for (int k = 0; k < KSTATE; ++k) s += __expf(T[lane * KSTATE + k] - m);
  float inv = 1.0f / s;
  for (int k = 0; k < KSTATE; ++k)
    expT[lane * KSTATE + k] = __expf(T[lane * KSTATE + k] - m) * inv;
  float x = pi[lane];
  float mm = x;
  #pragma unroll
  for (int off = 32; off >= 1; off >>= 1) mm = fmaxf(mm, __shfl_xor(mm, off, 64));
  float e = __expf(x - mm);
  #pragma unroll
  for (int off = 32; off >= 1; off >>= 1) e += __shfl_xor(e, off, 64);
  log_pi[lane] = x - mm - __logf(e);
  if (lane == 0) out[0] = 0.f;  // harness poisons d_out; we atomicAdd into it
}

// One wave per sequence, scaled-linear-domain forward recurrence.
//
// Round-5 broadcast: wave-UNIFORM ds_read_b128. One DS instruction broadcasts
// FOUR a[j] values to all 64 lanes (same-address LDS access = free broadcast,
// no bank conflict). Per step: 1 ds_write + 16 ds_read_b128 + 64 plain fma.
// Calibration (r2/r3/r4): plain fma = 2.0 cyc clean; v_readlane ~5-10 cyc
// regardless of scheduling; DPP-fmac ~6; per-value DS ops ~23. This is the
// instruction-minimal broadcast; the LDS write->read latency (~150-250) is
// pipelined against the 128-cyc fma stream (reads issued up front, consumed
// in order with staggered lgkmcnt waits; max 17 outstanding -> lgkmcnt(15)
// expressible). We are serial-latency-bound (1 seq per SIMD, 1024 seqs =
// 1024 SIMDs), so only critical-path length matters.
__global__ __launch_bounds__(256, 1) void hmm_forward(
    const float* __restrict__ log_pdf,
    const float* __restrict__ expT,
    const float* __restrict__ log_pi,
    float* __restrict__ out, int N) {
  __shared__ __align__(16) float abuf[4][KSTATE];  // wave-private rows
  const int lane = threadIdx.x & 63;
  const int wave = threadIdx.x >> 6;
  const int b = blockIdx.x * 4 + wave;
  float* ab = abuf[wave];

  // tcol[j] = expT[j][lane]  (column `lane` of the transition matrix)
  float tcol[KSTATE];
  #pragma unroll
  for (int j = 0; j < KSTATE; ++j) tcol[j] = expT[j * KSTATE + lane];

  const float* lp = log_pdf + (size_t)lane * (size_t)N + (size_t)b * NSAMP;

  float4 v0 = *(const float4*)(lp);        // group 0 (t=0..3)
  float4 r1 = *(const float4*)(lp + 4);
  float4 r2 = *(const float4*)(lp + 8);
  float4 r3 = *(const float4*)(lp + 12);

  float x0 = v0.x + log_pi[lane];
  float C = bcast0(x0);
  float a = __expf(x0 - C);

  // 4 MACs from quad Q into accumulators c0..c3 (even) / c4..c7 (odd).
#define MAC4A(Q, J) do {                                                      \
    c0 = fmaf(Q.x, tcol[(J)+0], c0); c1 = fmaf(Q.y, tcol[(J)+1], c1);         \
    c2 = fmaf(Q.z, tcol[(J)+2], c2); c3 = fmaf(Q.w, tcol[(J)+3], c3);         \
  } while (0)
#define MAC4B(Q, J) do {                                                      \
    c4 = fmaf(Q.x, tcol[(J)+0], c4); c5 = fmaf(Q.y, tcol[(J)+1], c5);         \
    c6 = fmaf(Q.z, tcol[(J)+2], c6); c7 = fmaf(Q.w, tcol[(J)+3], c7);         \
  } while (0)

#define STEP(E) do {                                                          \
    ab[lane] = a;                              /* ds_write_b32 */             \
    float4 Q0 = *(const float4*)(ab +  0);     /* 16x uniform ds_read_b128 */ \
    float4 Q1 = *(const float4*)(ab +  4);     /* each broadcasts 4 a[j]   */ \
    float4 Q2 = *(const float4*)(ab +  8);                                    \
    float4 Q3 = *(const float4*)(ab + 12);                                    \
    float4 Q4 = *(const float4*)(ab + 16);                                    \
    float4 Q5 = *(const float4*)(ab + 20);                                    \
    float4 Q6 = *(const float4*)(ab + 24);                                    \
    float4 Q7 = *(const float4*)(ab + 28);                                    \
    float4 Q8 = *(const float4*)(ab + 32);                                    \
    float4 Q9 = *(const float4*)(ab + 36);                                    \
    float4 QA = *(const float4*)(ab + 40);                                    \
    float4 QB = *(const float4*)(ab + 44);                                    \
    float4 QC = *(const float4*)(ab + 48);                                    \
    float4 QD = *(const float4*)(ab + 52);                                    \
    float4 QE = *(const float4*)(ab + 56);                                    \
    float4 QF = *(const float4*)(ab + 60);                                    \
    float c0 = Q0.x * tcol[0], c1 = Q0.y * tcol[1];                           \
    float c2 = Q0.z * tcol[2], c3 = Q0.w * tcol[3];                           \
    float c4 = Q1.x * tcol[4], c5 = Q1.y * tcol[5];                           \
    float c6 = Q1.z * tcol[6], c7 = Q1.w * tcol[7];                           \
    MAC4A(Q2,  8); MAC4B(Q3, 12);                                             \
    MAC4A(Q4, 16); MAC4B(Q5, 20);                                             \
    MAC4A(Q6, 24); MAC4B(Q7, 28);                                             \
    MAC4A(Q8, 32); MAC4B(Q9, 36);                                             \
    MAC4A(QA, 40); MAC4B(QB, 44);                                             \
    MAC4A(QC, 48); MAC4B(QD, 52);                                             \
    MAC4A(QE, 56); MAC4B(QF, 60);                                             \
    float sA = (c0 + c1) + (c2 + c3);                                         \
    float sB = (c4 + c5) + (c6 + c7);                                         \
    a = (sA + sB) * (E);                                                      \
  } while (0)

  // Renorm every 4 steps (range analysis: 4-step growth/decay stays well
  // inside fp32; identical math to the verified earlier rounds).
#define RENORM() do {                                                         \
    float c = bcast0(a);                                                      \
    a = a * __builtin_amdgcn_rcpf(c);                                         \
    C += __logf(c);                                                           \
  } while (0)

  {  // steps t = 1..3 from group 0
    float e1 = __expf(v0.y), e2 = __expf(v0.z), e3 = __expf(v0.w);
    STEP(e1); STEP(e2); STEP(e3);
    RENORM();
  }

  const int NG = NSAMP / 4;
  for (int g = 1; g < NG; ++g) {
    float4 v = r1; r1 = r2; r2 = r3;
    int gn = (g + 3 < NG) ? (g + 3) : (NG - 1);
    r3 = *(const float4*)(lp + 4 * gn);
    float e0 = __expf(v.x), e1 = __expf(v.y), e2 = __expf(v.z), e3 = __expf(v.w);
    STEP(e0); STEP(e1); STEP(e2); STEP(e3);
    RENORM();
  }
#undef STEP
#undef MAC4A
#undef MAC4B
#undef RENORM

  // out += C + log(sum_k a[k])
  float s = a;
  #pragma unroll
  for (int off = 32; off >= 1; off >>= 1) s += __shfl_xor(s, off, 64);
  if (lane == 0) atomicAdd(out, C + __logf(s));
}

extern "C" void kernel_launch(void* const* d_in, const int* in_sizes, int n_in,
                              void* d_out, int out_size, void* d_ws, size_t ws_size,
                              hipStream_t stream) {
  const float* log_pdf = (const float*)d_in[0];
  const float* pi      = (const float*)d_in[1];
  const float* T       = (const float*)d_in[2];
  float* out = (float*)d_out;

  float* expT   = (float*)d_ws;              // 64*64 floats
  float* log_pi = expT + KSTATE * KSTATE;    // 64 floats

  const int N = in_sizes[0] / KSTATE;        // 1048576
  const int B = N / NSAMP;                   // 1024 sequences

  hipLaunchKernelGGL(hmm_preproc, dim3(1), dim3(64), 0, stream,
                     pi, T, expT, log_pi, out);
  hipLaunchKernelGGL(hmm_forward, dim3(B / 4), dim3(256), 0, stream,
                     log_pdf, expT, log_pi, out, N);
}